// Round 13
// baseline (195.755 us; speedup 1.0000x reference)
//
#include <hip/hip_runtime.h>
#include <hip/hip_bf16.h>

#define NB   4
#define CIN  64
#define COUT 64
#define HH   160
#define WW   160
#define HW   (HH * WW)

typedef __attribute__((ext_vector_type(8))) short bf16x8;   // 8 bf16 = 4 VGPR
typedef __attribute__((ext_vector_type(4))) float f32x4;
typedef __attribute__((ext_vector_type(2))) float f32x2;
typedef __attribute__((ext_vector_type(4))) unsigned int u32x4;

static __device__ __forceinline__ short f2bf(float v) {
    return __builtin_bit_cast(short, __float2bfloat16(v));
}

// Keep-alive sinks (rule #17: ablation-via-skip DCEs upstream ops)
#define SINK4(v) do { u32x4 _s = __builtin_bit_cast(u32x4, v);               \
    asm volatile("" :: "v"(_s[0]), "v"(_s[1]), "v"(_s[2]), "v"(_s[3])); } while (0)
#define SINKF(x) asm volatile("" :: "v"(x))

// ---------------------------------------------------------------------------
// Pre-pass 1: weight [O][C][3][3] f32 -> wtf in exact A-fragment order.
// ---------------------------------------------------------------------------
__global__ void wtf_kernel(const float* __restrict__ w, short* __restrict__ wtf) {
    int i = blockIdx.x * 256 + threadIdx.x;   // 9*2*4*64*8 = 36864
    if (i < 36864) {
        const int j  = i & 7;
        const int l  = (i >> 3) & 63;
        const int mt = (i >> 9) & 3;
        const int ks = (i >> 11) & 1;
        const int t  = i >> 12;
        const int o  = 16 * mt + (l & 15);
        const int c  = 32 * ks + 8 * (l >> 4) + j;
        wtf[i] = f2bf(w[(o * CIN + c) * 9 + t]);
    }
}

// ---------------------------------------------------------------------------
// Pre-pass 2: input NCHW f32 -> tin NHWC bf16 (XCD-aligned writes).
// ---------------------------------------------------------------------------
__global__ __launch_bounds__(256) void tin_kernel(const float* __restrict__ in,
                                                  short* __restrict__ tin) {
    const int cpx = gridDim.x >> 3;
    const int wb  = (blockIdx.x & 7) * cpx + (blockIdx.x >> 3);
    const int gid = wb * 256 + threadIdx.x;
    if (gid >= NB * HW) return;
    const int b  = gid / HW;
    const int hw = gid - b * HW;
    const float* src = in + (size_t)b * CIN * HW + hw;
    short* dst = tin + (size_t)gid * CIN;
#pragma unroll
    for (int chunk = 0; chunk < 4; ++chunk) {
        union { u32x4 v; short s[8]; } p0, p1;
#pragma unroll
        for (int cc = 0; cc < 8; ++cc)
            p0.s[cc] = f2bf(src[(size_t)(chunk * 16 + cc) * HW]);
#pragma unroll
        for (int cc = 0; cc < 8; ++cc)
            p1.s[cc] = f2bf(src[(size_t)(chunk * 16 + 8 + cc) * HW]);
        *(u32x4*)(dst + chunk * 16)     = p0.v;
        *(u32x4*)(dst + chunk * 16 + 8) = p1.v;
    }
}

// Geometry for tap T -> 4 bilinear coefs + 4 corner pointers (from tb).
#define GEOM(T, C00, C01, C10, C11, Q00, Q01, Q10, Q11) do {                 \
    const int gky = (T) / 3, gkx = (T) - 3 * gky;                            \
    const float gsy = fy + (float)(gky - 1) * rate;                          \
    const float gsx = fx + (float)(gkx - 1) * rate;                          \
    const float gy0f = floorf(gsy), gx0f = floorf(gsx);                      \
    const float gwy = gsy - gy0f, gwx = gsx - gx0f;                          \
    const int gy0 = (int)gy0f, gx0 = (int)gx0f;                              \
    const int gy1 = gy0 + 1, gx1 = gx0 + 1;                                  \
    const float gomwy = 1.0f - gwy, gomwx = 1.0f - gwx;                      \
    const float gvy0 = (gy0 >= 0 && gy0 < HH) ? 1.0f : 0.0f;                 \
    const float gvy1 = (gy1 >= 0 && gy1 < HH) ? 1.0f : 0.0f;                 \
    const float gvx0 = (gx0 >= 0 && gx0 < WW) ? 1.0f : 0.0f;                 \
    const float gvx1 = (gx1 >= 0 && gx1 < WW) ? 1.0f : 0.0f;                 \
    C00 = gomwy * gomwx * gvy0 * gvx0;                                       \
    C01 = gomwy * gwx   * gvy0 * gvx1;                                       \
    C10 = gwy   * gomwx * gvy1 * gvx0;                                       \
    C11 = gwy   * gwx   * gvy1 * gvx1;                                       \
    const int gcy0 = min(max(gy0, 0), HH - 1);                               \
    const int gcy1 = min(max(gy1, 0), HH - 1);                               \
    const int gcx0 = min(max(gx0, 0), WW - 1);                               \
    const int gcx1 = min(max(gx1, 0), WW - 1);                               \
    Q00 = tb + (size_t)(gcy0 * WW + gcx0) * CIN;                             \
    Q01 = tb + (size_t)(gcy0 * WW + gcx1) * CIN;                             \
    Q10 = tb + (size_t)(gcy1 * WW + gcx0) * CIN;                             \
    Q11 = tb + (size_t)(gcy1 * WW + gcx1) * CIN;                             \
} while (0)

// shared per-thread index computation (R9 split-K form, grid 3200)
#define COMMON_IDX                                                           \
    const int tid   = threadIdx.x;                                           \
    const int wave  = tid >> 6;                                              \
    const int lane  = tid & 63;                                              \
    const int px    = lane & 15;                                             \
    const int g     = lane >> 4;                                             \
    const int strip = wave >> 1;                                             \
    const int ks    = wave & 1;                                              \
    const int cpx = gridDim.x >> 3;                                          \
    const int bid = (blockIdx.x & 7) * cpx + (blockIdx.x >> 3);              \
    const int base = bid * 32 + strip * 16;                                  \
    const int b    = base / HW;                                              \
    const int pix0 = base - b * HW;                                          \
    const int y    = pix0 / WW;                                              \
    const int x0   = pix0 - y * WW;                                          \
    const int x    = x0 + px;                                                \
    const float rate = rate_map[base + px];                                  \
    const float fy = (float)y, fx = (float)x;                                \
    const short* tb  = tin + (size_t)b * HW * CIN + 32 * ks + 8 * g;         \
    const short* wtb = wtf + (size_t)ks * 2048 + lane * 8;

// Blend 8 channels + 4 MFMA rank-updates (packed f32 + cvt_pk_bf16).
static __device__ __forceinline__ void consume_tap(
    const u32x4 v00, const u32x4 v01, const u32x4 v10, const u32x4 v11,
    const float c00, const float c01, const float c10, const float c11,
    const bf16x8 wf0, const bf16x8 wf1, const bf16x8 wf2, const bf16x8 wf3,
    f32x4 acc[4])
{
    union { bf16x8 v; unsigned u[4]; } pf;
#pragma unroll
    for (int wd = 0; wd < 4; ++wd) {
        f32x2 s;
        {
            const unsigned u0 = v00[wd];
            const f32x2 xv = { __builtin_bit_cast(float, u0 << 16),
                               __builtin_bit_cast(float, u0 & 0xffff0000u) };
            s = c00 * xv;
        }
        {
            const unsigned u0 = v01[wd];
            const f32x2 xv = { __builtin_bit_cast(float, u0 << 16),
                               __builtin_bit_cast(float, u0 & 0xffff0000u) };
            s += c01 * xv;
        }
        {
            const unsigned u0 = v10[wd];
            const f32x2 xv = { __builtin_bit_cast(float, u0 << 16),
                               __builtin_bit_cast(float, u0 & 0xffff0000u) };
            s += c10 * xv;
        }
        {
            const unsigned u0 = v11[wd];
            const f32x2 xv = { __builtin_bit_cast(float, u0 << 16),
                               __builtin_bit_cast(float, u0 & 0xffff0000u) };
            s += c11 * xv;
        }
        unsigned r;
        asm("v_cvt_pk_bf16_f32 %0, %1, %2" : "=v"(r) : "v"(s.x), "v"(s.y));
        pf.u[wd] = r;
    }
    acc[0] = __builtin_amdgcn_mfma_f32_16x16x32_bf16(wf0, pf.v, acc[0], 0, 0, 0);
    acc[1] = __builtin_amdgcn_mfma_f32_16x16x32_bf16(wf1, pf.v, acc[1], 0, 0, 0);
    acc[2] = __builtin_amdgcn_mfma_f32_16x16x32_bf16(wf2, pf.v, acc[2], 0, 0, 0);
    acc[3] = __builtin_amdgcn_mfma_f32_16x16x32_bf16(wf3, pf.v, acc[3], 0, 0, 0);
}

// ===========================================================================
// ABLATION 1: geometry + ALL loads, no blend/MFMA (results sunk, kept live).
// ===========================================================================
__global__ __launch_bounds__(256, 3) void abl_loads(
    const short* __restrict__ tin, const short* __restrict__ wtf,
    const float* __restrict__ rate_map, float* __restrict__ wsab)
{
    COMMON_IDX
    float c00, c01, c10, c11;
    const short *q00, *q01, *q10, *q11;
    GEOM(0, c00, c01, c10, c11, q00, q01, q10, q11);
    u32x4 v00 = *(const u32x4*)q00, v01 = *(const u32x4*)q01;
    u32x4 v10 = *(const u32x4*)q10, v11 = *(const u32x4*)q11;
    bf16x8 wf0 = *(const bf16x8*)(wtb);
    bf16x8 wf1 = *(const bf16x8*)(wtb + 512);
    bf16x8 wf2 = *(const bf16x8*)(wtb + 1024);
    bf16x8 wf3 = *(const bf16x8*)(wtb + 1536);

#pragma unroll 1
    for (int t = 0; t < 9; ++t) {
        float n00 = 0.f, n01 = 0.f, n10 = 0.f, n11 = 0.f;
        u32x4 m00, m01, m10, m11;
        bf16x8 nf0, nf1, nf2, nf3;
        if (t < 8) {
            const short *r00, *r01, *r10, *r11;
            GEOM(t + 1, n00, n01, n10, n11, r00, r01, r10, r11);
            m00 = *(const u32x4*)r00; m01 = *(const u32x4*)r01;
            m10 = *(const u32x4*)r10; m11 = *(const u32x4*)r11;
            const short* wb = wtb + (size_t)(t + 1) * 4096;
            nf0 = *(const bf16x8*)(wb);
            nf1 = *(const bf16x8*)(wb + 512);
            nf2 = *(const bf16x8*)(wb + 1024);
            nf3 = *(const bf16x8*)(wb + 1536);
        }
        // consume point: keep tap-t data live (replaces blend+MFMA)
        SINK4(v00); SINK4(v01); SINK4(v10); SINK4(v11);
        SINK4(wf0); SINK4(wf1); SINK4(wf2); SINK4(wf3);
        SINKF(c00); SINKF(c01); SINKF(c10); SINKF(c11);
        v00 = m00; v01 = m01; v10 = m10; v11 = m11;
        wf0 = nf0; wf1 = nf1; wf2 = nf2; wf3 = nf3;
        c00 = n00; c01 = n01; c10 = n10; c11 = n11;
    }
    wsab[blockIdx.x * 256 + tid] = rate;
}

// ===========================================================================
// ABLATION 2: geometry + blend + MFMA, ZERO loop VMEM (fabricated data).
// ===========================================================================
__global__ __launch_bounds__(256, 3) void abl_compute(
    const short* __restrict__ tin, const short* __restrict__ wtf,
    const float* __restrict__ rate_map, float* __restrict__ wsab)
{
    COMMON_IDX
    (void)wtb;
    const unsigned ur = __builtin_bit_cast(unsigned, rate);
    const u32x4 v00 = {ur, ur + 1u, ur + 2u, ur + 3u};
    const u32x4 v01 = {ur ^ 5u, ur ^ 9u, ur ^ 13u, ur ^ 17u};
    const u32x4 v10 = {ur + 7u, ur + 11u, ur + 19u, ur + 23u};
    const u32x4 v11 = {ur ^ 21u, ur ^ 25u, ur ^ 29u, ur ^ 33u};
    union { bf16x8 v; short s[8]; } uw;
#pragma unroll
    for (int j = 0; j < 8; ++j) uw.s[j] = (short)(lane * 131 + j);
    const bf16x8 wf0 = uw.v;
#pragma unroll
    for (int j = 0; j < 8; ++j) uw.s[j] = (short)(lane * 37 + j * 3);
    const bf16x8 wf1 = uw.v;
#pragma unroll
    for (int j = 0; j < 8; ++j) uw.s[j] = (short)(lane * 53 + j * 5);
    const bf16x8 wf2 = uw.v;
#pragma unroll
    for (int j = 0; j < 8; ++j) uw.s[j] = (short)(lane * 71 + j * 7);
    const bf16x8 wf3 = uw.v;

    f32x4 acc[4];
#pragma unroll
    for (int mt = 0; mt < 4; ++mt) acc[mt] = (f32x4){0.f, 0.f, 0.f, 0.f};

#pragma unroll 1
    for (int t = 0; t < 9; ++t) {
        float c00, c01, c10, c11;
        const short *q00, *q01, *q10, *q11;
        GEOM(t, c00, c01, c10, c11, q00, q01, q10, q11);
        // keep the address-calc VALU live (same as full kernel)
        SINKF((unsigned)(size_t)q00); SINKF((unsigned)(size_t)q01);
        SINKF((unsigned)(size_t)q10); SINKF((unsigned)(size_t)q11);
        consume_tap(v00, v01, v10, v11, c00, c01, c10, c11,
                    wf0, wf1, wf2, wf3, acc);
    }
    SINK4(acc[1]); SINK4(acc[2]); SINK4(acc[3]);
    wsab[blockIdx.x * 256 + tid] = acc[0][0] + acc[0][1] + acc[0][2] + acc[0][3];
}

// ===========================================================================
// ABLATION 3: full pipeline, but all corner loads from ONE wave-uniform
// pixel record (~2 segments/load instead of 16; L1-hot after tap 0).
// ===========================================================================
__global__ __launch_bounds__(256, 3) void abl_uniform(
    const short* __restrict__ tin, const short* __restrict__ wtf,
    const float* __restrict__ rate_map, float* __restrict__ wsab)
{
    COMMON_IDX
    const short* qc = tb + (size_t)pix0 * CIN;   // strip-base pixel (uniform)

    f32x4 acc[4];
#pragma unroll
    for (int mt = 0; mt < 4; ++mt) acc[mt] = (f32x4){0.f, 0.f, 0.f, 0.f};

    float c00, c01, c10, c11;
    {
        const short *r00, *r01, *r10, *r11;
        GEOM(0, c00, c01, c10, c11, r00, r01, r10, r11);
        SINKF((unsigned)(size_t)r00); SINKF((unsigned)(size_t)r01);
        SINKF((unsigned)(size_t)r10); SINKF((unsigned)(size_t)r11);
    }
    u32x4 v00 = *(const u32x4*)(qc);
    u32x4 v01 = *(const u32x4*)(qc + 8);
    u32x4 v10 = *(const u32x4*)(qc + 16);
    u32x4 v11 = *(const u32x4*)(qc + 24);
    bf16x8 wf0 = *(const bf16x8*)(wtb);
    bf16x8 wf1 = *(const bf16x8*)(wtb + 512);
    bf16x8 wf2 = *(const bf16x8*)(wtb + 1024);
    bf16x8 wf3 = *(const bf16x8*)(wtb + 1536);

#pragma unroll 1
    for (int t = 0; t < 9; ++t) {
        float n00 = 0.f, n01 = 0.f, n10 = 0.f, n11 = 0.f;
        u32x4 m00, m01, m10, m11;
        bf16x8 nf0, nf1, nf2, nf3;
        if (t < 8) {
            const short *r00, *r01, *r10, *r11;
            GEOM(t + 1, n00, n01, n10, n11, r00, r01, r10, r11);
            SINKF((unsigned)(size_t)r00); SINKF((unsigned)(size_t)r01);
            SINKF((unsigned)(size_t)r10); SINKF((unsigned)(size_t)r11);
            m00 = *(const u32x4*)(qc);
            m01 = *(const u32x4*)(qc + 8);
            m10 = *(const u32x4*)(qc + 16);
            m11 = *(const u32x4*)(qc + 24);
            const short* wb = wtb + (size_t)(t + 1) * 4096;
            nf0 = *(const bf16x8*)(wb);
            nf1 = *(const bf16x8*)(wb + 512);
            nf2 = *(const bf16x8*)(wb + 1024);
            nf3 = *(const bf16x8*)(wb + 1536);
        }
        consume_tap(v00, v01, v10, v11, c00, c01, c10, c11,
                    wf0, wf1, wf2, wf3, acc);
        v00 = m00; v01 = m01; v10 = m10; v11 = m11;
        wf0 = nf0; wf1 = nf1; wf2 = nf2; wf3 = nf3;
        c00 = n00; c01 = n01; c10 = n10; c11 = n11;
    }
    SINK4(acc[1]); SINK4(acc[2]); SINK4(acc[3]);
    wsab[blockIdx.x * 256 + tid] = acc[0][0] + acc[0][1] + acc[0][2] + acc[0][3];
}

// ===========================================================================
// REAL kernel (R9 split-K form, 74.5 µs reference) -> d_out.
// ===========================================================================
__global__ __launch_bounds__(256, 3) void pdconv_split_kernel(
    const short* __restrict__ tin, const short* __restrict__ wtf,
    const float* __restrict__ rate_map, const float* __restrict__ bias,
    float* __restrict__ out)
{
    COMMON_IDX

    f32x4 acc[4];
#pragma unroll
    for (int mt = 0; mt < 4; ++mt) acc[mt] = (f32x4){0.f, 0.f, 0.f, 0.f};

    float c00, c01, c10, c11;
    const short *q00, *q01, *q10, *q11;
    GEOM(0, c00, c01, c10, c11, q00, q01, q10, q11);
    u32x4 v00 = *(const u32x4*)q00, v01 = *(const u32x4*)q01;
    u32x4 v10 = *(const u32x4*)q10, v11 = *(const u32x4*)q11;
    bf16x8 wf0 = *(const bf16x8*)(wtb);
    bf16x8 wf1 = *(const bf16x8*)(wtb + 512);
    bf16x8 wf2 = *(const bf16x8*)(wtb + 1024);
    bf16x8 wf3 = *(const bf16x8*)(wtb + 1536);

#pragma unroll 1
    for (int t = 0; t < 9; ++t) {
        float n00 = 0.f, n01 = 0.f, n10 = 0.f, n11 = 0.f;
        u32x4 m00, m01, m10, m11;
        bf16x8 nf0, nf1, nf2, nf3;
        if (t < 8) {
            const short *r00, *r01, *r10, *r11;
            GEOM(t + 1, n00, n01, n10, n11, r00, r01, r10, r11);
            m00 = *(const u32x4*)r00; m01 = *(const u32x4*)r01;
            m10 = *(const u32x4*)r10; m11 = *(const u32x4*)r11;
            const short* wb = wtb + (size_t)(t + 1) * 4096;
            nf0 = *(const bf16x8*)(wb);
            nf1 = *(const bf16x8*)(wb + 512);
            nf2 = *(const bf16x8*)(wb + 1024);
            nf3 = *(const bf16x8*)(wb + 1536);
        }
        consume_tap(v00, v01, v10, v11, c00, c01, c10, c11,
                    wf0, wf1, wf2, wf3, acc);
        v00 = m00; v01 = m01; v10 = m10; v11 = m11;
        wf0 = nf0; wf1 = nf1; wf2 = nf2; wf3 = nf3;
        c00 = n00; c01 = n01; c10 = n10; c11 = n11;
    }

    __shared__ float red[2][64][17];     // stride 17: gcd(17,32)=1 -> free
    if (ks == 1) {
#pragma unroll
        for (int mt = 0; mt < 4; ++mt)
#pragma unroll
            for (int r = 0; r < 4; ++r)
                red[strip][lane][4 * mt + r] = acc[mt][r];
    }
    __syncthreads();
    if (ks == 0) {
        float* op = out + (size_t)b * COUT * HW + pix0 + px;
#pragma unroll
        for (int mt = 0; mt < 4; ++mt) {
            const f32x4 bv = *(const f32x4*)(bias + 16 * mt + 4 * g);
#pragma unroll
            for (int r = 0; r < 4; ++r) {
                const int o = 16 * mt + 4 * g + r;
                op[(size_t)o * HW] = acc[mt][r] + red[strip][lane][4 * mt + r] + bv[r];
            }
        }
    }
}

// ---------------------------------------------------------------------------
// Fallback (round-7 NCHW path) if ws_size is too small.
// ---------------------------------------------------------------------------
__global__ void wt2_kernel(const float* __restrict__ w, short* __restrict__ wt2) {
    int i = blockIdx.x * 256 + threadIdx.x;
    if (i < 9 * COUT * CIN) {
        int c = i & 63, o = (i >> 6) & 63, t = i >> 12;
        wt2[i] = f2bf(w[(o * CIN + c) * 9 + t]);
    }
}

__global__ __launch_bounds__(256) void pdconv_mfma_kernel(
    const float* __restrict__ in, const short* __restrict__ wt2,
    const float* __restrict__ rate_map, const float* __restrict__ bias,
    float* __restrict__ out)
{
    const int tid = threadIdx.x, wave = tid >> 6, lane = tid & 63;
    const int px = lane & 15, g = lane >> 4;
    const int cpx = gridDim.x >> 3;
    const int bid = (blockIdx.x & 7) * cpx + (blockIdx.x >> 3);
    const int base = bid * 64 + wave * 16;
    const int b = base / HW, pix0 = base - b * HW;
    const int y = pix0 / WW, x0 = pix0 - y * WW, x = x0 + px;
    const float rate = rate_map[base + px];
    const float fy = (float)y, fx = (float)x;
    f32x4 acc[4];
#pragma unroll
    for (int mt = 0; mt < 4; ++mt) acc[mt] = (f32x4){0.f, 0.f, 0.f, 0.f};
    const float* img  = in + (size_t)b * CIN * HW;
    const float* imgg = img + (size_t)g * 8 * HW;
#pragma unroll 1
    for (int t = 0; t < 9; ++t) {
        const int ky = t / 3, kx = t - 3 * ky;
        const float sy = fy + (float)(ky - 1) * rate;
        const float sx = fx + (float)(kx - 1) * rate;
        const float y0f = floorf(sy), x0f = floorf(sx);
        const float wy = sy - y0f, wx = sx - x0f;
        const int y0 = (int)y0f, x0i = (int)x0f, y1 = y0 + 1, x1 = x0i + 1;
        const float omwy = 1.0f - wy, omwx = 1.0f - wx;
        const float vy0 = (y0 >= 0 && y0 < HH) ? 1.0f : 0.0f;
        const float vy1 = (y1 >= 0 && y1 < HH) ? 1.0f : 0.0f;
        const float vx0 = (x0i >= 0 && x0i < WW) ? 1.0f : 0.0f;
        const float vx1 = (x1 >= 0 && x1 < WW) ? 1.0f : 0.0f;
        const float c00 = omwy * omwx * vy0 * vx0, c01 = omwy * wx * vy0 * vx1;
        const float c10 = wy * omwx * vy1 * vx0,  c11 = wy * wx * vy1 * vx1;
        const int cy0 = min(max(y0, 0), HH - 1), cy1 = min(max(y1, 0), HH - 1);
        const int cx0 = min(max(x0i, 0), WW - 1), cx1 = min(max(x1, 0), WW - 1);
        const int i00 = cy0 * WW + cx0, i01 = cy0 * WW + cx1;
        const int i10 = cy1 * WW + cx0, i11 = cy1 * WW + cx1;
#pragma unroll
        for (int ks = 0; ks < 2; ++ks) {
            bf16x8 wf[4];
#pragma unroll
            for (int mt = 0; mt < 4; ++mt)
                wf[mt] = *(const bf16x8*)(wt2 +
                          ((t * COUT + 16 * mt + px) * CIN + 32 * ks + 8 * g));
            float a[8];
#pragma unroll
            for (int j = 0; j < 8; ++j) {
                const float* ch = imgg + (size_t)(32 * ks + j) * HW;
                a[j] = c00 * ch[i00] + c01 * ch[i01] + c10 * ch[i10] + c11 * ch[i11];
            }
            union { bf16x8 v; short s[8]; } pf;
#pragma unroll
            for (int j = 0; j < 8; ++j) pf.s[j] = f2bf(a[j]);
#pragma unroll
            for (int mt = 0; mt < 4; ++mt)
                acc[mt] = __builtin_amdgcn_mfma_f32_16x16x32_bf16(
                              wf[mt], pf.v, acc[mt], 0, 0, 0);
        }
    }
    float* op = out + (size_t)b * COUT * HW + pix0 + px;
#pragma unroll
    for (int mt = 0; mt < 4; ++mt)
#pragma unroll
        for (int r = 0; r < 4; ++r) {
            const int o = 16 * mt + 4 * g + r;
            op[(size_t)o * HW] = acc[mt][r] + bias[o];
        }
}

extern "C" void kernel_launch(void* const* d_in, const int* in_sizes, int n_in,
                              void* d_out, int out_size, void* d_ws, size_t ws_size,
                              hipStream_t stream) {
    (void)in_sizes; (void)n_in; (void)out_size;
    const float* in   = (const float*)d_in[0];
    const float* w    = (const float*)d_in[1];
    const float* rm   = (const float*)d_in[2];
    const float* bias = (const float*)d_in[3];
    float* out = (float*)d_out;

    const size_t WTF_BYTES = 36864 * sizeof(short);                 // 73,728
    const size_t TIN_BYTES = (size_t)NB * HW * CIN * sizeof(short); // 13,107,200
    const size_t ABL_BYTES = (size_t)3200 * 256 * sizeof(float);    // 3,276,800
    const int nblocks = (NB * HW) / 32;                             // 3200

    if (ws_size >= WTF_BYTES + TIN_BYTES + ABL_BYTES) {
        short* wtf = (short*)d_ws;
        short* tin = (short*)((char*)d_ws + WTF_BYTES);
        float* wsab = (float*)((char*)d_ws + WTF_BYTES + TIN_BYTES);
        hipLaunchKernelGGL(wtf_kernel, dim3(144), dim3(256), 0, stream, w, wtf);
        hipLaunchKernelGGL(tin_kernel, dim3((NB * HW) / 256), dim3(256),
                           0, stream, in, tin);
        // ---- ablation dispatches (diagnostic; results go to scratch) ----
        hipLaunchKernelGGL(abl_loads,   dim3(nblocks), dim3(256), 0, stream,
                           tin, wtf, rm, wsab);
        hipLaunchKernelGGL(abl_compute, dim3(nblocks), dim3(256), 0, stream,
                           tin, wtf, rm, wsab);
        hipLaunchKernelGGL(abl_uniform, dim3(nblocks), dim3(256), 0, stream,
                           tin, wtf, rm, wsab);
        // ---- real kernel ----
        hipLaunchKernelGGL(pdconv_split_kernel, dim3(nblocks), dim3(256), 0,
                           stream, tin, wtf, rm, bias, out);
    } else if (ws_size >= WTF_BYTES + TIN_BYTES) {
        short* wtf = (short*)d_ws;
        short* tin = (short*)((char*)d_ws + WTF_BYTES);
        hipLaunchKernelGGL(wtf_kernel, dim3(144), dim3(256), 0, stream, w, wtf);
        hipLaunchKernelGGL(tin_kernel, dim3((NB * HW) / 256), dim3(256),
                           0, stream, in, tin);
        hipLaunchKernelGGL(pdconv_split_kernel, dim3(nblocks), dim3(256), 0,
                           stream, tin, wtf, rm, bias, out);
    } else {
        short* wt2 = (short*)d_ws;   // 73,728 B
        hipLaunchKernelGGL(wt2_kernel, dim3(144), dim3(256), 0, stream, w, wt2);
        hipLaunchKernelGGL(pdconv_mfma_kernel, dim3((NB * HW) / 64), dim3(256),
                           0, stream, in, wt2, rm, bias, out);
    }
}

// Round 14
// 49.316 us; speedup vs baseline: 3.9694x; 3.9694x over previous
//
#include <hip/hip_runtime.h>
#include <hip/hip_bf16.h>

#define NB   4
#define CIN  64
#define COUT 64
#define HH   160
#define WW   160
#define HW   (HH * WW)

// halo tile geometry: 2x32 output tile, rate<3 => support rows oy..oy+8,
// cols ox..ox+38 where oy=2r-3, ox=32c-3.
#define RT   9
#define CT   39
#define RS   72              // record stride in shorts (144 B: 64ch + 8 pad)
#define HIN_SHORTS (RT * CT * RS)   // 25272 shorts = 50544 B

typedef __attribute__((ext_vector_type(8))) short bf16x8;   // 8 bf16 = 4 VGPR
typedef __attribute__((ext_vector_type(4))) float f32x4;
typedef __attribute__((ext_vector_type(2))) float f32x2;
typedef __attribute__((ext_vector_type(4))) unsigned int u32x4;

static __device__ __forceinline__ short f2bf(float v) {
    return __builtin_bit_cast(short, __float2bfloat16(v));
}

// ---------------------------------------------------------------------------
// Pre-pass 1: weight [O][C][3][3] f32 -> wtf in exact A-fragment order:
// wtf[t][ks][mt][lane][j]; frag (t,ks,mt) = contiguous 1 KB, lane reads 16 B.
//   o = 16*mt + (lane&15),  c = 32*ks + 8*(lane>>4) + j
// ---------------------------------------------------------------------------
__global__ void wtf_kernel(const float* __restrict__ w, short* __restrict__ wtf) {
    int i = blockIdx.x * 256 + threadIdx.x;   // 9*2*4*64*8 = 36864
    if (i < 36864) {
        const int j  = i & 7;
        const int l  = (i >> 3) & 63;
        const int mt = (i >> 9) & 3;
        const int ks = (i >> 11) & 1;
        const int t  = i >> 12;
        const int o  = 16 * mt + (l & 15);
        const int c  = 32 * ks + 8 * (l >> 4) + j;
        wtf[i] = f2bf(w[(o * CIN + c) * 9 + t]);
    }
}

// ---------------------------------------------------------------------------
// Pre-pass 2: input [B][C][H][W] f32 -> tin [B][H][W][C] bf16 (XCD-aligned).
// ---------------------------------------------------------------------------
__global__ __launch_bounds__(256) void tin_kernel(const float* __restrict__ in,
                                                  short* __restrict__ tin) {
    const int cpx = gridDim.x >> 3;
    const int wb  = (blockIdx.x & 7) * cpx + (blockIdx.x >> 3);
    const int gid = wb * 256 + threadIdx.x;
    if (gid >= NB * HW) return;
    const int b  = gid / HW;
    const int hw = gid - b * HW;
    const float* src = in + (size_t)b * CIN * HW + hw;
    short* dst = tin + (size_t)gid * CIN;
#pragma unroll
    for (int chunk = 0; chunk < 4; ++chunk) {
        union { u32x4 v; short s[8]; } p0, p1;
#pragma unroll
        for (int cc = 0; cc < 8; ++cc)
            p0.s[cc] = f2bf(src[(size_t)(chunk * 16 + cc) * HW]);
#pragma unroll
        for (int cc = 0; cc < 8; ++cc)
            p1.s[cc] = f2bf(src[(size_t)(chunk * 16 + 8 + cc) * HW]);
        *(u32x4*)(dst + chunk * 16)     = p0.v;
        *(u32x4*)(dst + chunk * 16 + 8) = p1.v;
    }
}

// Blend 8 channels (4 dwords of packed bf16 pairs) + 4 MFMA rank-updates.
static __device__ __forceinline__ void consume_tap(
    const u32x4 v00, const u32x4 v01, const u32x4 v10, const u32x4 v11,
    const float c00, const float c01, const float c10, const float c11,
    const bf16x8 wf0, const bf16x8 wf1, const bf16x8 wf2, const bf16x8 wf3,
    f32x4 acc[4])
{
    union { bf16x8 v; unsigned u[4]; } pf;
#pragma unroll
    for (int wd = 0; wd < 4; ++wd) {
        f32x2 s;
        {
            const unsigned u0 = v00[wd];
            const f32x2 xv = { __builtin_bit_cast(float, u0 << 16),
                               __builtin_bit_cast(float, u0 & 0xffff0000u) };
            s = c00 * xv;
        }
        {
            const unsigned u0 = v01[wd];
            const f32x2 xv = { __builtin_bit_cast(float, u0 << 16),
                               __builtin_bit_cast(float, u0 & 0xffff0000u) };
            s += c01 * xv;
        }
        {
            const unsigned u0 = v10[wd];
            const f32x2 xv = { __builtin_bit_cast(float, u0 << 16),
                               __builtin_bit_cast(float, u0 & 0xffff0000u) };
            s += c10 * xv;
        }
        {
            const unsigned u0 = v11[wd];
            const f32x2 xv = { __builtin_bit_cast(float, u0 << 16),
                               __builtin_bit_cast(float, u0 & 0xffff0000u) };
            s += c11 * xv;
        }
        unsigned r;
        asm("v_cvt_pk_bf16_f32 %0, %1, %2" : "=v"(r) : "v"(s.x), "v"(s.y));
        pf.u[wd] = r;
    }
    acc[0] = __builtin_amdgcn_mfma_f32_16x16x32_bf16(wf0, pf.v, acc[0], 0, 0, 0);
    acc[1] = __builtin_amdgcn_mfma_f32_16x16x32_bf16(wf1, pf.v, acc[1], 0, 0, 0);
    acc[2] = __builtin_amdgcn_mfma_f32_16x16x32_bf16(wf2, pf.v, acc[2], 0, 0, 0);
    acc[3] = __builtin_amdgcn_mfma_f32_16x16x32_bf16(wf3, pf.v, acc[3], 0, 0, 0);
}

// ---------------------------------------------------------------------------
// Main kernel (LDS halo): block = 2 rows x 32 cols of output (64 px), 4
// waves of 16 px, FULL K per wave. The bilinear support region (9 rows x
// 39 cols x 64 ch bf16, edge-clamped) is staged into LDS once (coalesced
// 16 B chunks, record stride 144 B -> consecutive records shift 4 banks ->
// <=2-way conflicts = free). Gathers become ds_read_b128 (~120 cyc lat,
// 12 cyc tput) instead of 16-line divergent VMEM (R13 ablation: the VMEM
// gather path serialized with compute ~= the whole 74.5 us).
// Tile coords need NO clamp: ty = y0-oy in [0,8], tx = x0-ox in [0,38]
// by construction (rate < 3), and staged rows/cols are themselves clamped
// so LDS[ty][tx] == image[clamp(y0)][clamp(x0)].
// ---------------------------------------------------------------------------
__global__ __launch_bounds__(256, 2) void pdconv_halo_kernel(
    const short* __restrict__ tin,       // [B][H][W][CIN] bf16
    const short* __restrict__ wtf,       // frag-ordered weights bf16
    const float* __restrict__ rate_map,  // [B][1][H][W] f32
    const float* __restrict__ bias,      // [COUT] f32
    float* __restrict__ out)             // [B][COUT][H][W] f32
{
    __shared__ short hin[HIN_SHORTS];    // 50,544 B

    const int tid  = threadIdx.x;
    const int wave = tid >> 6;
    const int lane = tid & 63;
    const int px   = lane & 15;
    const int g    = lane >> 4;

    // XCD-bijective swizzle (1600 % 8 == 0)
    const int cpx = gridDim.x >> 3;                     // 200
    const int bid = (blockIdx.x & 7) * cpx + (blockIdx.x >> 3);

    // bid -> (b, row-pair rr, col-block cc): 80 pairs x 5 col-blocks / image
    const int b   = bid / 400;
    const int rem = bid - b * 400;
    const int rr  = rem / 5;
    const int cc  = rem - rr * 5;
    const int oy  = 2 * rr - 3;
    const int ox  = 32 * cc - 3;

    // ---- stage halo tile -> LDS (coalesced; edges clamped) ----
    const short* ib = tin + (size_t)b * HW * CIN;
#pragma unroll
    for (int it = 0; it < 11; ++it) {
        const int idx = it * 256 + tid;              // chunk id
        if (idx < RT * CT * 8) {
            const int rec = idx >> 3;
            const int cp  = idx & 7;
            const int ty  = rec / CT;
            const int tx  = rec - ty * CT;
            const int gy  = min(max(oy + ty, 0), HH - 1);
            const int gx  = min(max(ox + tx, 0), WW - 1);
            const u32x4 v = *(const u32x4*)(ib + ((size_t)gy * WW + gx) * CIN + cp * 8);
            *(u32x4*)(hin + rec * RS + cp * 8) = v;
        }
    }
    __syncthreads();

    // ---- per-wave output strip: row = 2rr + (wave>>1), cols 32cc+16(wave&1).. ----
    const int row = 2 * rr + (wave >> 1);
    const int col0 = 32 * cc + 16 * (wave & 1);
    const int x   = col0 + px;
    const float rate = rate_map[b * HW + row * WW + x];
    const float fy = (float)row, fx = (float)x;

    const short* wtb = wtf + lane * 8;               // + frag*512

    f32x4 acc[4];
#pragma unroll
    for (int mt = 0; mt < 4; ++mt) acc[mt] = (f32x4){0.f, 0.f, 0.f, 0.f};

#pragma unroll 1
    for (int t = 0; t < 9; ++t) {
        const int ky = t / 3;
        const int kx = t - 3 * ky;

        // geometry (validity from original coords; addresses from tile coords)
        const float sy  = fy + (float)(ky - 1) * rate;
        const float sx  = fx + (float)(kx - 1) * rate;
        const float y0f = floorf(sy), x0f = floorf(sx);
        const float wy  = sy - y0f,   wx  = sx - x0f;
        const int   y0  = (int)y0f,   x0i = (int)x0f;
        const int   y1  = y0 + 1,     x1  = x0i + 1;

        const float omwy = 1.0f - wy, omwx = 1.0f - wx;
        const float vy0 = (y0 >= 0 && y0 < HH) ? 1.0f : 0.0f;
        const float vy1 = (y1 >= 0 && y1 < HH) ? 1.0f : 0.0f;
        const float vx0 = (x0i >= 0 && x0i < WW) ? 1.0f : 0.0f;
        const float vx1 = (x1 >= 0 && x1 < WW) ? 1.0f : 0.0f;

        const float c00 = omwy * omwx * vy0 * vx0;
        const float c01 = omwy * wx   * vy0 * vx1;
        const float c10 = wy   * omwx * vy1 * vx0;
        const float c11 = wy   * wx   * vy1 * vx1;

        // tile records: in-range by construction (rate < 3)
        const int rec00 = (y0 - oy) * CT + (x0i - ox);
        const short* h00 = hin + rec00 * RS + 8 * g;

        // 8 LDS gathers (16 B each; 2 K-halves x 4 corners)
        u32x4 v00[2], v01[2], v10[2], v11[2];
#pragma unroll
        for (int ks = 0; ks < 2; ++ks) {
            const short* hk = h00 + 32 * ks;
            v00[ks] = *(const u32x4*)(hk);
            v01[ks] = *(const u32x4*)(hk + RS);           // (y0, x1)
            v10[ks] = *(const u32x4*)(hk + CT * RS);      // (y1, x0)
            v11[ks] = *(const u32x4*)(hk + (CT + 1) * RS);// (y1, x1)
        }

        // weights (global, L2-hot 72 KB) + blend + MFMA per K-half
#pragma unroll
        for (int ks = 0; ks < 2; ++ks) {
            const short* wb = wtb + (size_t)((t * 2 + ks) * 4) * 512;
            const bf16x8 wf0 = *(const bf16x8*)(wb);
            const bf16x8 wf1 = *(const bf16x8*)(wb + 512);
            const bf16x8 wf2 = *(const bf16x8*)(wb + 1024);
            const bf16x8 wf3 = *(const bf16x8*)(wb + 1536);
            consume_tap(v00[ks], v01[ks], v10[ks], v11[ks],
                        c00, c01, c10, c11, wf0, wf1, wf2, wf3, acc);
        }
    }

    // ---- epilogue: C col = px, row = 4g + r (+16mt) ----
    float* op = out + (size_t)b * COUT * HW + row * WW + col0 + px;
#pragma unroll
    for (int mt = 0; mt < 4; ++mt) {
        const f32x4 bv = *(const f32x4*)(bias + 16 * mt + 4 * g);
#pragma unroll
        for (int r = 0; r < 4; ++r) {
            const int o = 16 * mt + 4 * g + r;
            op[(size_t)o * HW] = acc[mt][r] + bv[r];
        }
    }
}

// ---------------------------------------------------------------------------
// Fallback (round-7 NCHW path) if ws_size is too small.
// ---------------------------------------------------------------------------
__global__ void wt2_kernel(const float* __restrict__ w, short* __restrict__ wt2) {
    int i = blockIdx.x * 256 + threadIdx.x;
    if (i < 9 * COUT * CIN) {
        int c = i & 63, o = (i >> 6) & 63, t = i >> 12;
        wt2[i] = f2bf(w[(o * CIN + c) * 9 + t]);
    }
}

__global__ __launch_bounds__(256) void pdconv_mfma_kernel(
    const float* __restrict__ in, const short* __restrict__ wt2,
    const float* __restrict__ rate_map, const float* __restrict__ bias,
    float* __restrict__ out)
{
    const int tid = threadIdx.x, wave = tid >> 6, lane = tid & 63;
    const int px = lane & 15, g = lane >> 4;
    const int cpx = gridDim.x >> 3;
    const int bid = (blockIdx.x & 7) * cpx + (blockIdx.x >> 3);
    const int base = bid * 64 + wave * 16;
    const int b = base / HW, pix0 = base - b * HW;
    const int y = pix0 / WW, x0 = pix0 - y * WW, x = x0 + px;
    const float rate = rate_map[base + px];
    const float fy = (float)y, fx = (float)x;
    f32x4 acc[4];
#pragma unroll
    for (int mt = 0; mt < 4; ++mt) acc[mt] = (f32x4){0.f, 0.f, 0.f, 0.f};
    const float* img  = in + (size_t)b * CIN * HW;
    const float* imgg = img + (size_t)g * 8 * HW;
#pragma unroll 1
    for (int t = 0; t < 9; ++t) {
        const int ky = t / 3, kx = t - 3 * ky;
        const float sy = fy + (float)(ky - 1) * rate;
        const float sx = fx + (float)(kx - 1) * rate;
        const float y0f = floorf(sy), x0f = floorf(sx);
        const float wy = sy - y0f, wx = sx - x0f;
        const int y0 = (int)y0f, x0i = (int)x0f, y1 = y0 + 1, x1 = x0i + 1;
        const float omwy = 1.0f - wy, omwx = 1.0f - wx;
        const float vy0 = (y0 >= 0 && y0 < HH) ? 1.0f : 0.0f;
        const float vy1 = (y1 >= 0 && y1 < HH) ? 1.0f : 0.0f;
        const float vx0 = (x0i >= 0 && x0i < WW) ? 1.0f : 0.0f;
        const float vx1 = (x1 >= 0 && x1 < WW) ? 1.0f : 0.0f;
        const float c00 = omwy * omwx * vy0 * vx0, c01 = omwy * wx * vy0 * vx1;
        const float c10 = wy * omwx * vy1 * vx0,  c11 = wy * wx * vy1 * vx1;
        const int cy0 = min(max(y0, 0), HH - 1), cy1 = min(max(y1, 0), HH - 1);
        const int cx0 = min(max(x0i, 0), WW - 1), cx1 = min(max(x1, 0), WW - 1);
        const int i00 = cy0 * WW + cx0, i01 = cy0 * WW + cx1;
        const int i10 = cy1 * WW + cx0, i11 = cy1 * WW + cx1;
#pragma unroll
        for (int ks = 0; ks < 2; ++ks) {
            bf16x8 wf[4];
#pragma unroll
            for (int mt = 0; mt < 4; ++mt)
                wf[mt] = *(const bf16x8*)(wt2 +
                          ((t * COUT + 16 * mt + px) * CIN + 32 * ks + 8 * g));
            float a[8];
#pragma unroll
            for (int j = 0; j < 8; ++j) {
                const float* ch = imgg + (size_t)(32 * ks + j) * HW;
                a[j] = c00 * ch[i00] + c01 * ch[i01] + c10 * ch[i10] + c11 * ch[i11];
            }
            union { bf16x8 v; short s[8]; } pf;
#pragma unroll
            for (int j = 0; j < 8; ++j) pf.s[j] = f2bf(a[j]);
#pragma unroll
            for (int mt = 0; mt < 4; ++mt)
                acc[mt] = __builtin_amdgcn_mfma_f32_16x16x32_bf16(
                              wf[mt], pf.v, acc[mt], 0, 0, 0);
        }
    }
    float* op = out + (size_t)b * COUT * HW + pix0 + px;
#pragma unroll
    for (int mt = 0; mt < 4; ++mt)
#pragma unroll
        for (int r = 0; r < 4; ++r) {
            const int o = 16 * mt + 4 * g + r;
            op[(size_t)o * HW] = acc[mt][r] + bias[o];
        }
}

extern "C" void kernel_launch(void* const* d_in, const int* in_sizes, int n_in,
                              void* d_out, int out_size, void* d_ws, size_t ws_size,
                              hipStream_t stream) {
    (void)in_sizes; (void)n_in; (void)out_size;
    const float* in   = (const float*)d_in[0];
    const float* w    = (const float*)d_in[1];
    const float* rm   = (const float*)d_in[2];
    const float* bias = (const float*)d_in[3];
    float* out = (float*)d_out;

    const size_t WTF_BYTES = 36864 * sizeof(short);                 // 73,728
    const size_t TIN_BYTES = (size_t)NB * HW * CIN * sizeof(short); // 13,107,200

    if (ws_size >= WTF_BYTES + TIN_BYTES) {
        short* wtf = (short*)d_ws;
        short* tin = (short*)((char*)d_ws + WTF_BYTES);
        hipLaunchKernelGGL(wtf_kernel, dim3(144), dim3(256), 0, stream, w, wtf);
        hipLaunchKernelGGL(tin_kernel, dim3((NB * HW) / 256), dim3(256),
                           0, stream, in, tin);
        const int nblocks = NB * 80 * 5;   // 1600: 2x32 tiles
        hipLaunchKernelGGL(pdconv_halo_kernel, dim3(nblocks), dim3(256), 0,
                           stream, tin, wtf, rm, bias, out);
    } else {
        short* wt2 = (short*)d_ws;   // 73,728 B
        hipLaunchKernelGGL(wt2_kernel, dim3(144), dim3(256), 0, stream, w, wt2);
        hipLaunchKernelGGL(pdconv_mfma_kernel, dim3((NB * HW) / 64), dim3(256),
                           0, stream, in, wt2, rm, bias, out);
    }
}

// Round 15
// 46.777 us; speedup vs baseline: 4.1848x; 1.0543x over previous
//
#include <hip/hip_runtime.h>
#include <hip/hip_bf16.h>

#define NB   4
#define CIN  64
#define COUT 64
#define HH   160
#define WW   160
#define HW   (HH * WW)

// halo tile geometry: 2x32 output tile, rate<3 => support rows oy..oy+8,
// cols ox..ox+38 where oy=2r-3, ox=32c-3.
#define RT   9
#define CT   39
#define RS   72              // record stride in shorts (144 B: 64ch + 8 pad)
#define HIN_SHORTS (RT * CT * RS)   // 25272 shorts = 50544 B (3 blocks/CU OK)

typedef __attribute__((ext_vector_type(8))) short bf16x8;   // 8 bf16 = 4 VGPR
typedef __attribute__((ext_vector_type(4))) float f32x4;
typedef __attribute__((ext_vector_type(2))) float f32x2;
typedef __attribute__((ext_vector_type(4))) unsigned int u32x4;

static __device__ __forceinline__ short f2bf(float v) {
    return __builtin_bit_cast(short, __float2bfloat16(v));
}

// ---------------------------------------------------------------------------
// Pre-pass 1: weight [O][C][3][3] f32 -> wtf in exact A-fragment order:
// wtf[t][ks][mt][lane][j]; frag (t,ks,mt) = contiguous 1 KB, lane reads 16 B.
// ---------------------------------------------------------------------------
__global__ void wtf_kernel(const float* __restrict__ w, short* __restrict__ wtf) {
    int i = blockIdx.x * 256 + threadIdx.x;   // 9*2*4*64*8 = 36864
    if (i < 36864) {
        const int j  = i & 7;
        const int l  = (i >> 3) & 63;
        const int mt = (i >> 9) & 3;
        const int ks = (i >> 11) & 1;
        const int t  = i >> 12;
        const int o  = 16 * mt + (l & 15);
        const int c  = 32 * ks + 8 * (l >> 4) + j;
        wtf[i] = f2bf(w[(o * CIN + c) * 9 + t]);
    }
}

// ---------------------------------------------------------------------------
// Pre-pass 2: input [B][C][H][W] f32 -> tin [B][H][W][C] bf16 (XCD-aligned).
// ---------------------------------------------------------------------------
__global__ __launch_bounds__(256) void tin_kernel(const float* __restrict__ in,
                                                  short* __restrict__ tin) {
    const int cpx = gridDim.x >> 3;
    const int wb  = (blockIdx.x & 7) * cpx + (blockIdx.x >> 3);
    const int gid = wb * 256 + threadIdx.x;
    if (gid >= NB * HW) return;
    const int b  = gid / HW;
    const int hw = gid - b * HW;
    const float* src = in + (size_t)b * CIN * HW + hw;
    short* dst = tin + (size_t)gid * CIN;
#pragma unroll
    for (int chunk = 0; chunk < 4; ++chunk) {
        union { u32x4 v; short s[8]; } p0, p1;
#pragma unroll
        for (int cc = 0; cc < 8; ++cc)
            p0.s[cc] = f2bf(src[(size_t)(chunk * 16 + cc) * HW]);
#pragma unroll
        for (int cc = 0; cc < 8; ++cc)
            p1.s[cc] = f2bf(src[(size_t)(chunk * 16 + 8 + cc) * HW]);
        *(u32x4*)(dst + chunk * 16)     = p0.v;
        *(u32x4*)(dst + chunk * 16 + 8) = p1.v;
    }
}

// Blend 8 channels (4 dwords of packed bf16 pairs) + 4 MFMA rank-updates.
static __device__ __forceinline__ void consume_tap(
    const u32x4 v00, const u32x4 v01, const u32x4 v10, const u32x4 v11,
    const float c00, const float c01, const float c10, const float c11,
    const bf16x8 wf0, const bf16x8 wf1, const bf16x8 wf2, const bf16x8 wf3,
    f32x4 acc[4])
{
    union { bf16x8 v; unsigned u[4]; } pf;
#pragma unroll
    for (int wd = 0; wd < 4; ++wd) {
        f32x2 s;
        {
            const unsigned u0 = v00[wd];
            const f32x2 xv = { __builtin_bit_cast(float, u0 << 16),
                               __builtin_bit_cast(float, u0 & 0xffff0000u) };
            s = c00 * xv;
        }
        {
            const unsigned u0 = v01[wd];
            const f32x2 xv = { __builtin_bit_cast(float, u0 << 16),
                               __builtin_bit_cast(float, u0 & 0xffff0000u) };
            s += c01 * xv;
        }
        {
            const unsigned u0 = v10[wd];
            const f32x2 xv = { __builtin_bit_cast(float, u0 << 16),
                               __builtin_bit_cast(float, u0 & 0xffff0000u) };
            s += c10 * xv;
        }
        {
            const unsigned u0 = v11[wd];
            const f32x2 xv = { __builtin_bit_cast(float, u0 << 16),
                               __builtin_bit_cast(float, u0 & 0xffff0000u) };
            s += c11 * xv;
        }
        unsigned r;
        asm("v_cvt_pk_bf16_f32 %0, %1, %2" : "=v"(r) : "v"(s.x), "v"(s.y));
        pf.u[wd] = r;
    }
    acc[0] = __builtin_amdgcn_mfma_f32_16x16x32_bf16(wf0, pf.v, acc[0], 0, 0, 0);
    acc[1] = __builtin_amdgcn_mfma_f32_16x16x32_bf16(wf1, pf.v, acc[1], 0, 0, 0);
    acc[2] = __builtin_amdgcn_mfma_f32_16x16x32_bf16(wf2, pf.v, acc[2], 0, 0, 0);
    acc[3] = __builtin_amdgcn_mfma_f32_16x16x32_bf16(wf3, pf.v, acc[3], 0, 0, 0);
}

// ---------------------------------------------------------------------------
// Main kernel (LDS halo + depth-1 LDS pipeline): block = 2x32 output tile,
// 4 waves of 16 px, full K per wave. Halo (9x39x64ch bf16, edge-clamped,
// 144 B record stride) staged to LDS once; gathers are ds_read_b128.
// Fully-unrolled tap loop, 2-slot rolling window: tap t+1's geometry +
// 8 ds_reads issue BEFORE tap t's blend/MFMA (LDS latency ~120 cyc hides
// under ~200 cyc of blend VALU). Weights load at consume (L2-hot; latency
// hides under the blend preceding their MFMA use).
// launch_bounds(256,3): LDS 50544*3 = 151632 < 160K -> 3 blocks/CU.
// ---------------------------------------------------------------------------
__global__ __launch_bounds__(256, 3) void pdconv_halo_kernel(
    const short* __restrict__ tin,       // [B][H][W][CIN] bf16
    const short* __restrict__ wtf,       // frag-ordered weights bf16
    const float* __restrict__ rate_map,  // [B][1][H][W] f32
    const float* __restrict__ bias,      // [COUT] f32
    float* __restrict__ out)             // [B][COUT][H][W] f32
{
    __shared__ short hin[HIN_SHORTS];    // 50,544 B

    const int tid  = threadIdx.x;
    const int wave = tid >> 6;
    const int lane = tid & 63;
    const int px   = lane & 15;
    const int g    = lane >> 4;

    // XCD-bijective swizzle (1600 % 8 == 0)
    const int cpx = gridDim.x >> 3;                     // 200
    const int bid = (blockIdx.x & 7) * cpx + (blockIdx.x >> 3);

    // bid -> (b, row-pair rr, col-block cc): 80 pairs x 5 col-blocks / image
    const int b   = bid / 400;
    const int rem = bid - b * 400;
    const int rr  = rem / 5;
    const int cc  = rem - rr * 5;
    const int oy  = 2 * rr - 3;
    const int ox  = 32 * cc - 3;

    // ---- stage halo tile -> LDS (coalesced; edges clamped) ----
    const short* ib = tin + (size_t)b * HW * CIN;
#pragma unroll
    for (int it = 0; it < 11; ++it) {
        const int idx = it * 256 + tid;              // chunk id
        if (idx < RT * CT * 8) {
            const int rec = idx >> 3;
            const int cp  = idx & 7;
            const int ty  = rec / CT;
            const int tx  = rec - ty * CT;
            const int gy  = min(max(oy + ty, 0), HH - 1);
            const int gx  = min(max(ox + tx, 0), WW - 1);
            const u32x4 v = *(const u32x4*)(ib + ((size_t)gy * WW + gx) * CIN + cp * 8);
            *(u32x4*)(hin + rec * RS + cp * 8) = v;
        }
    }

    // ---- per-wave output strip ----
    const int row  = 2 * rr + (wave >> 1);
    const int col0 = 32 * cc + 16 * (wave & 1);
    const int x    = col0 + px;
    const float rate = rate_map[b * HW + row * WW + x];
    const float fy = (float)row, fx = (float)x;

    const short* wtb = wtf + lane * 8;               // + frag*512

    f32x4 acc[4];
#pragma unroll
    for (int mt = 0; mt < 4; ++mt) acc[mt] = (f32x4){0.f, 0.f, 0.f, 0.f};

    // ---- rolling windows: 2 slots, all indices compile-time ----
    u32x4 vi00[2][2], vi01[2][2], vi10[2][2], vi11[2][2];
    float cf[2][4];

    // geometry for tap T -> coefs into cf[SL], LDS base pointer H0
#define GEOMH(T, SL, H0) do {                                                \
    const int gky = (T) / 3, gkx = (T) - 3 * gky;                            \
    const float gsy = fy + (float)(gky - 1) * rate;                          \
    const float gsx = fx + (float)(gkx - 1) * rate;                          \
    const float gy0f = floorf(gsy), gx0f = floorf(gsx);                      \
    const float gwy = gsy - gy0f, gwx = gsx - gx0f;                          \
    const int gy0 = (int)gy0f, gx0 = (int)gx0f;                              \
    const float gomwy = 1.0f - gwy, gomwx = 1.0f - gwx;                      \
    const float gvy0 = (gy0 >= 0 && gy0 < HH) ? 1.0f : 0.0f;                 \
    const float gvy1 = (gy0 + 1 >= 0 && gy0 + 1 < HH) ? 1.0f : 0.0f;         \
    const float gvx0 = (gx0 >= 0 && gx0 < WW) ? 1.0f : 0.0f;                 \
    const float gvx1 = (gx0 + 1 >= 0 && gx0 + 1 < WW) ? 1.0f : 0.0f;         \
    cf[SL][0] = gomwy * gomwx * gvy0 * gvx0;                                 \
    cf[SL][1] = gomwy * gwx   * gvy0 * gvx1;                                 \
    cf[SL][2] = gwy   * gomwx * gvy1 * gvx0;                                 \
    cf[SL][3] = gwy   * gwx   * gvy1 * gvx1;                                 \
    H0 = hin + ((gy0 - oy) * CT + (gx0 - ox)) * RS + 8 * g;                  \
} while (0)

#define LOADIN(T, SL) do {                                                   \
    const short* h00;                                                        \
    GEOMH(T, SL, h00);                                                       \
    _Pragma("unroll")                                                        \
    for (int ks = 0; ks < 2; ++ks) {                                         \
        const short* hk = h00 + 32 * ks;                                     \
        vi00[SL][ks] = *(const u32x4*)(hk);                                  \
        vi01[SL][ks] = *(const u32x4*)(hk + RS);                             \
        vi10[SL][ks] = *(const u32x4*)(hk + CT * RS);                        \
        vi11[SL][ks] = *(const u32x4*)(hk + (CT + 1) * RS);                  \
    }                                                                        \
} while (0)

    __syncthreads();           // halo staged
    LOADIN(0, 0);              // prologue: tap-0 gathers

#pragma unroll
    for (int t = 0; t < 9; ++t) {
        const int s = t & 1;                       // constant after unroll
        if (t < 8) LOADIN(t + 1, (t + 1) & 1);     // depth-1 LDS prefetch
#pragma unroll
        for (int ks = 0; ks < 2; ++ks) {
            const short* wb = wtb + (size_t)((t * 2 + ks) * 4) * 512;
            const bf16x8 wf0 = *(const bf16x8*)(wb);
            const bf16x8 wf1 = *(const bf16x8*)(wb + 512);
            const bf16x8 wf2 = *(const bf16x8*)(wb + 1024);
            const bf16x8 wf3 = *(const bf16x8*)(wb + 1536);
            consume_tap(vi00[s][ks], vi01[s][ks], vi10[s][ks], vi11[s][ks],
                        cf[s][0], cf[s][1], cf[s][2], cf[s][3],
                        wf0, wf1, wf2, wf3, acc);
        }
    }
#undef LOADIN
#undef GEOMH

    // ---- epilogue: C col = px, row = 4g + r (+16mt) ----
    float* op = out + (size_t)b * COUT * HW + row * WW + col0 + px;
#pragma unroll
    for (int mt = 0; mt < 4; ++mt) {
        const f32x4 bv = *(const f32x4*)(bias + 16 * mt + 4 * g);
#pragma unroll
        for (int r = 0; r < 4; ++r) {
            const int o = 16 * mt + 4 * g + r;
            op[(size_t)o * HW] = acc[mt][r] + bv[r];
        }
    }
}

// ---------------------------------------------------------------------------
// Fallback (round-7 NCHW path) if ws_size is too small.
// ---------------------------------------------------------------------------
__global__ void wt2_kernel(const float* __restrict__ w, short* __restrict__ wt2) {
    int i = blockIdx.x * 256 + threadIdx.x;
    if (i < 9 * COUT * CIN) {
        int c = i & 63, o = (i >> 6) & 63, t = i >> 12;
        wt2[i] = f2bf(w[(o * CIN + c) * 9 + t]);
    }
}

__global__ __launch_bounds__(256) void pdconv_mfma_kernel(
    const float* __restrict__ in, const short* __restrict__ wt2,
    const float* __restrict__ rate_map, const float* __restrict__ bias,
    float* __restrict__ out)
{
    const int tid = threadIdx.x, wave = tid >> 6, lane = tid & 63;
    const int px = lane & 15, g = lane >> 4;
    const int cpx = gridDim.x >> 3;
    const int bid = (blockIdx.x & 7) * cpx + (blockIdx.x >> 3);
    const int base = bid * 64 + wave * 16;
    const int b = base / HW, pix0 = base - b * HW;
    const int y = pix0 / WW, x0 = pix0 - y * WW, x = x0 + px;
    const float rate = rate_map[base + px];
    const float fy = (float)y, fx = (float)x;
    f32x4 acc[4];
#pragma unroll
    for (int mt = 0; mt < 4; ++mt) acc[mt] = (f32x4){0.f, 0.f, 0.f, 0.f};
    const float* img  = in + (size_t)b * CIN * HW;
    const float* imgg = img + (size_t)g * 8 * HW;
#pragma unroll 1
    for (int t = 0; t < 9; ++t) {
        const int ky = t / 3, kx = t - 3 * ky;
        const float sy = fy + (float)(ky - 1) * rate;
        const float sx = fx + (float)(kx - 1) * rate;
        const float y0f = floorf(sy), x0f = floorf(sx);
        const float wy = sy - y0f, wx = sx - x0f;
        const int y0 = (int)y0f, x0i = (int)x0f, y1 = y0 + 1, x1 = x0i + 1;
        const float omwy = 1.0f - wy, omwx = 1.0f - wx;
        const float vy0 = (y0 >= 0 && y0 < HH) ? 1.0f : 0.0f;
        const float vy1 = (y1 >= 0 && y1 < HH) ? 1.0f : 0.0f;
        const float vx0 = (x0i >= 0 && x0i < WW) ? 1.0f : 0.0f;
        const float vx1 = (x1 >= 0 && x1 < WW) ? 1.0f : 0.0f;
        const float c00 = omwy * omwx * vy0 * vx0, c01 = omwy * wx * vy0 * vx1;
        const float c10 = wy * omwx * vy1 * vx0,  c11 = wy * wx * vy1 * vx1;
        const int cy0 = min(max(y0, 0), HH - 1), cy1 = min(max(y1, 0), HH - 1);
        const int cx0 = min(max(x0i, 0), WW - 1), cx1 = min(max(x1, 0), WW - 1);
        const int i00 = cy0 * WW + cx0, i01 = cy0 * WW + cx1;
        const int i10 = cy1 * WW + cx0, i11 = cy1 * WW + cx1;
#pragma unroll
        for (int ks = 0; ks < 2; ++ks) {
            bf16x8 wf[4];
#pragma unroll
            for (int mt = 0; mt < 4; ++mt)
                wf[mt] = *(const bf16x8*)(wt2 +
                          ((t * COUT + 16 * mt + px) * CIN + 32 * ks + 8 * g));
            float a[8];
#pragma unroll
            for (int j = 0; j < 8; ++j) {
                const float* ch = imgg + (size_t)(32 * ks + j) * HW;
                a[j] = c00 * ch[i00] + c01 * ch[i01] + c10 * ch[i10] + c11 * ch[i11];
            }
            union { bf16x8 v; short s[8]; } pf;
#pragma unroll
            for (int j = 0; j < 8; ++j) pf.s[j] = f2bf(a[j]);
#pragma unroll
            for (int mt = 0; mt < 4; ++mt)
                acc[mt] = __builtin_amdgcn_mfma_f32_16x16x32_bf16(
                              wf[mt], pf.v, acc[mt], 0, 0, 0);
        }
    }
    float* op = out + (size_t)b * COUT * HW + pix0 + px;
#pragma unroll
    for (int mt = 0; mt < 4; ++mt)
#pragma unroll
        for (int r = 0; r < 4; ++r) {
            const int o = 16 * mt + 4 * g + r;
            op[(size_t)o * HW] = acc[mt][r] + bias[o];
        }
}

extern "C" void kernel_launch(void* const* d_in, const int* in_sizes, int n_in,
                              void* d_out, int out_size, void* d_ws, size_t ws_size,
                              hipStream_t stream) {
    (void)in_sizes; (void)n_in; (void)out_size;
    const float* in   = (const float*)d_in[0];
    const float* w    = (const float*)d_in[1];
    const float* rm   = (const float*)d_in[2];
    const float* bias = (const float*)d_in[3];
    float* out = (float*)d_out;

    const size_t WTF_BYTES = 36864 * sizeof(short);                 // 73,728
    const size_t TIN_BYTES = (size_t)NB * HW * CIN * sizeof(short); // 13,107,200

    if (ws_size >= WTF_BYTES + TIN_BYTES) {
        short* wtf = (short*)d_ws;
        short* tin = (short*)((char*)d_ws + WTF_BYTES);
        hipLaunchKernelGGL(wtf_kernel, dim3(144), dim3(256), 0, stream, w, wtf);
        hipLaunchKernelGGL(tin_kernel, dim3((NB * HW) / 256), dim3(256),
                           0, stream, in, tin);
        const int nblocks = NB * 80 * 5;   // 1600: 2x32 tiles
        hipLaunchKernelGGL(pdconv_halo_kernel, dim3(nblocks), dim3(256), 0,
                           stream, tin, wtf, rm, bias, out);
    } else {
        short* wt2 = (short*)d_ws;   // 73,728 B
        hipLaunchKernelGGL(wt2_kernel, dim3(144), dim3(256), 0, stream, w, wt2);
        hipLaunchKernelGGL(pdconv_mfma_kernel, dim3((NB * HW) / 64), dim3(256),
                           0, stream, in, wt2, rm, bias, out);
    }
}

// Round 16
// 46.488 us; speedup vs baseline: 4.2108x; 1.0062x over previous
//
#include <hip/hip_runtime.h>
#include <hip/hip_bf16.h>

#define NB   4
#define CIN  64
#define COUT 64
#define HH   160
#define WW   160
#define HW   (HH * WW)

// halo tile geometry: 2x32 output tile, rate<3 (strict) =>
// rows 2rr-3 .. 2rr+4 (8), cols 32cc-3 .. 32cc+34 (38).
#define RT   8
#define CT   38
#define RS   72              // record stride in shorts (144 B: 64ch + 8 pad)
#define HIN_SHORTS (RT * CT * RS)   // 21888 shorts = 43776 B -> 3 blocks/CU

typedef __attribute__((ext_vector_type(8))) short bf16x8;   // 8 bf16 = 4 VGPR
typedef __attribute__((ext_vector_type(4))) float f32x4;
typedef __attribute__((ext_vector_type(2))) float f32x2;
typedef __attribute__((ext_vector_type(4))) unsigned int u32x4;

static __device__ __forceinline__ short f2bf(float v) {
    return __builtin_bit_cast(short, __float2bfloat16(v));
}

// ---------------------------------------------------------------------------
// Pre-pass 1: weight [O][C][3][3] f32 -> wtf in exact A-fragment order:
// wtf[t][ks][mt][lane][j]; frag (t,ks,mt) = contiguous 1 KB, lane reads 16 B.
// ---------------------------------------------------------------------------
__global__ void wtf_kernel(const float* __restrict__ w, short* __restrict__ wtf) {
    int i = blockIdx.x * 256 + threadIdx.x;   // 9*2*4*64*8 = 36864
    if (i < 36864) {
        const int j  = i & 7;
        const int l  = (i >> 3) & 63;
        const int mt = (i >> 9) & 3;
        const int ks = (i >> 11) & 1;
        const int t  = i >> 12;
        const int o  = 16 * mt + (l & 15);
        const int c  = 32 * ks + 8 * (l >> 4) + j;
        wtf[i] = f2bf(w[(o * CIN + c) * 9 + t]);
    }
}

// ---------------------------------------------------------------------------
// Pre-pass 2: input [B][C][H][W] f32 -> tin [B][H][W][C] bf16 (XCD-aligned).
// ---------------------------------------------------------------------------
__global__ __launch_bounds__(256) void tin_kernel(const float* __restrict__ in,
                                                  short* __restrict__ tin) {
    const int cpx = gridDim.x >> 3;
    const int wb  = (blockIdx.x & 7) * cpx + (blockIdx.x >> 3);
    const int gid = wb * 256 + threadIdx.x;
    if (gid >= NB * HW) return;
    const int b  = gid / HW;
    const int hw = gid - b * HW;
    const float* src = in + (size_t)b * CIN * HW + hw;
    short* dst = tin + (size_t)gid * CIN;
#pragma unroll
    for (int chunk = 0; chunk < 4; ++chunk) {
        union { u32x4 v; short s[8]; } p0, p1;
#pragma unroll
        for (int cc = 0; cc < 8; ++cc)
            p0.s[cc] = f2bf(src[(size_t)(chunk * 16 + cc) * HW]);
#pragma unroll
        for (int cc = 0; cc < 8; ++cc)
            p1.s[cc] = f2bf(src[(size_t)(chunk * 16 + 8 + cc) * HW]);
        *(u32x4*)(dst + chunk * 16)     = p0.v;
        *(u32x4*)(dst + chunk * 16 + 8) = p1.v;
    }
}

// Blend 8 channels (4 dwords of packed bf16 pairs) + 4 MFMA rank-updates.
static __device__ __forceinline__ void consume_tap(
    const u32x4 v00, const u32x4 v01, const u32x4 v10, const u32x4 v11,
    const float c00, const float c01, const float c10, const float c11,
    const bf16x8 wf0, const bf16x8 wf1, const bf16x8 wf2, const bf16x8 wf3,
    f32x4 acc[4])
{
    union { bf16x8 v; unsigned u[4]; } pf;
#pragma unroll
    for (int wd = 0; wd < 4; ++wd) {
        f32x2 s;
        {
            const unsigned u0 = v00[wd];
            const f32x2 xv = { __builtin_bit_cast(float, u0 << 16),
                               __builtin_bit_cast(float, u0 & 0xffff0000u) };
            s = c00 * xv;
        }
        {
            const unsigned u0 = v01[wd];
            const f32x2 xv = { __builtin_bit_cast(float, u0 << 16),
                               __builtin_bit_cast(float, u0 & 0xffff0000u) };
            s += c01 * xv;
        }
        {
            const unsigned u0 = v10[wd];
            const f32x2 xv = { __builtin_bit_cast(float, u0 << 16),
                               __builtin_bit_cast(float, u0 & 0xffff0000u) };
            s += c10 * xv;
        }
        {
            const unsigned u0 = v11[wd];
            const f32x2 xv = { __builtin_bit_cast(float, u0 << 16),
                               __builtin_bit_cast(float, u0 & 0xffff0000u) };
            s += c11 * xv;
        }
        unsigned r;
        asm("v_cvt_pk_bf16_f32 %0, %1, %2" : "=v"(r) : "v"(s.x), "v"(s.y));
        pf.u[wd] = r;
    }
    acc[0] = __builtin_amdgcn_mfma_f32_16x16x32_bf16(wf0, pf.v, acc[0], 0, 0, 0);
    acc[1] = __builtin_amdgcn_mfma_f32_16x16x32_bf16(wf1, pf.v, acc[1], 0, 0, 0);
    acc[2] = __builtin_amdgcn_mfma_f32_16x16x32_bf16(wf2, pf.v, acc[2], 0, 0, 0);
    acc[3] = __builtin_amdgcn_mfma_f32_16x16x32_bf16(wf3, pf.v, acc[3], 0, 0, 0);
}

// ---------------------------------------------------------------------------
// Main kernel (LDS halo, tight 8x38 tile): block = 2x32 output tile, 4 waves
// of 16 px, full K per wave. Halo (8x38x64ch bf16, edge-clamped, 144 B
// record stride) staged to LDS once; gathers are ds_read_b128.
// LDS = 43,776 B -> 3 blocks/CU (R15's occupancy lever: 50.7 KB only gave
// 2 resident). Depth-1 rolling windows for BOTH input ds_reads and weight
// global loads (static indices); compiler may still collapse them (R15:
// VGPR 68 proves it serialized the window) — occupancy lever stands alone.
// ---------------------------------------------------------------------------
__global__ __launch_bounds__(256, 3) void pdconv_halo_kernel(
    const short* __restrict__ tin,       // [B][H][W][CIN] bf16
    const short* __restrict__ wtf,       // frag-ordered weights bf16
    const float* __restrict__ rate_map,  // [B][1][H][W] f32
    const float* __restrict__ bias,      // [COUT] f32
    float* __restrict__ out)             // [B][COUT][H][W] f32
{
    __shared__ short hin[HIN_SHORTS];    // 43,776 B

    const int tid  = threadIdx.x;
    const int wave = tid >> 6;
    const int lane = tid & 63;
    const int px   = lane & 15;
    const int g    = lane >> 4;

    // XCD-bijective swizzle (1600 % 8 == 0)
    const int cpx = gridDim.x >> 3;                     // 200
    const int bid = (blockIdx.x & 7) * cpx + (blockIdx.x >> 3);

    // bid -> (b, row-pair rr, col-block cc): 80 pairs x 5 col-blocks / image
    const int b   = bid / 400;
    const int rem = bid - b * 400;
    const int rr  = rem / 5;
    const int cc  = rem - rr * 5;
    const int oy  = 2 * rr - 3;
    const int ox  = 32 * cc - 3;

    // ---- stage halo tile -> LDS (coalesced; edges clamped) ----
    const short* ib = tin + (size_t)b * HW * CIN;
#pragma unroll
    for (int it = 0; it < 10; ++it) {
        const int idx = it * 256 + tid;              // chunk id
        if (idx < RT * CT * 8) {
            const int rec = idx >> 3;
            const int cp  = idx & 7;
            const int ty  = rec / CT;
            const int tx  = rec - ty * CT;
            const int gy  = min(max(oy + ty, 0), HH - 1);
            const int gx  = min(max(ox + tx, 0), WW - 1);
            const u32x4 v = *(const u32x4*)(ib + ((size_t)gy * WW + gx) * CIN + cp * 8);
            *(u32x4*)(hin + rec * RS + cp * 8) = v;
        }
    }

    // ---- per-wave output strip ----
    const int row  = 2 * rr + (wave >> 1);
    const int col0 = 32 * cc + 16 * (wave & 1);
    const int x    = col0 + px;
    const float rate = rate_map[b * HW + row * WW + x];
    const float fy = (float)row, fx = (float)x;

    const short* wtb = wtf + lane * 8;               // + frag*512

    f32x4 acc[4];
#pragma unroll
    for (int mt = 0; mt < 4; ++mt) acc[mt] = (f32x4){0.f, 0.f, 0.f, 0.f};

    // ---- rolling windows: 2 slots each, all indices compile-time ----
    u32x4 vi00[2][2], vi01[2][2], vi10[2][2], vi11[2][2];
    float cf[2][4];
    bf16x8 wfr[2][8];                                // [slot][ks*4+mt]

#define GEOMH(T, SL, H0) do {                                                \
    const int gky = (T) / 3, gkx = (T) - 3 * gky;                            \
    const float gsy = fy + (float)(gky - 1) * rate;                          \
    const float gsx = fx + (float)(gkx - 1) * rate;                          \
    const float gy0f = floorf(gsy), gx0f = floorf(gsx);                      \
    const float gwy = gsy - gy0f, gwx = gsx - gx0f;                          \
    const int gy0 = (int)gy0f, gx0 = (int)gx0f;                              \
    const float gomwy = 1.0f - gwy, gomwx = 1.0f - gwx;                      \
    const float gvy0 = (gy0 >= 0 && gy0 < HH) ? 1.0f : 0.0f;                 \
    const float gvy1 = (gy0 + 1 >= 0 && gy0 + 1 < HH) ? 1.0f : 0.0f;         \
    const float gvx0 = (gx0 >= 0 && gx0 < WW) ? 1.0f : 0.0f;                 \
    const float gvx1 = (gx0 + 1 >= 0 && gx0 + 1 < WW) ? 1.0f : 0.0f;         \
    cf[SL][0] = gomwy * gomwx * gvy0 * gvx0;                                 \
    cf[SL][1] = gomwy * gwx   * gvy0 * gvx1;                                 \
    cf[SL][2] = gwy   * gomwx * gvy1 * gvx0;                                 \
    cf[SL][3] = gwy   * gwx   * gvy1 * gvx1;                                 \
    H0 = hin + ((gy0 - oy) * CT + (gx0 - ox)) * RS + 8 * g;                  \
} while (0)

#define LOADIN(T, SL) do {                                                   \
    const short* h00;                                                        \
    GEOMH(T, SL, h00);                                                       \
    _Pragma("unroll")                                                        \
    for (int ks = 0; ks < 2; ++ks) {                                         \
        const short* hk = h00 + 32 * ks;                                     \
        vi00[SL][ks] = *(const u32x4*)(hk);                                  \
        vi01[SL][ks] = *(const u32x4*)(hk + RS);                             \
        vi10[SL][ks] = *(const u32x4*)(hk + CT * RS);                        \
        vi11[SL][ks] = *(const u32x4*)(hk + (CT + 1) * RS);                  \
    }                                                                        \
} while (0)

#define LOADW(T, SL) do {                                                    \
    _Pragma("unroll")                                                        \
    for (int ks = 0; ks < 2; ++ks)                                           \
        _Pragma("unroll")                                                    \
        for (int mt = 0; mt < 4; ++mt)                                       \
            wfr[SL][ks * 4 + mt] = *(const bf16x8*)(wtb +                    \
                (size_t)(((T) * 2 + ks) * 4 + mt) * 512);                    \
} while (0)

    LOADW(0, 0);               // weights need no barrier
    __syncthreads();           // halo staged
    LOADIN(0, 0);              // prologue: tap-0 gathers

#pragma unroll
    for (int t = 0; t < 9; ++t) {
        const int s = t & 1;                       // constant after unroll
        if (t < 8) {
            LOADIN(t + 1, (t + 1) & 1);            // depth-1 LDS prefetch
            LOADW(t + 1, (t + 1) & 1);             // depth-1 weight prefetch
        }
#pragma unroll
        for (int ks = 0; ks < 2; ++ks)
            consume_tap(vi00[s][ks], vi01[s][ks], vi10[s][ks], vi11[s][ks],
                        cf[s][0], cf[s][1], cf[s][2], cf[s][3],
                        wfr[s][ks * 4 + 0], wfr[s][ks * 4 + 1],
                        wfr[s][ks * 4 + 2], wfr[s][ks * 4 + 3], acc);
    }
#undef LOADIN
#undef LOADW
#undef GEOMH

    // ---- epilogue: C col = px, row = 4g + r (+16mt) ----
    float* op = out + (size_t)b * COUT * HW + row * WW + col0 + px;
#pragma unroll
    for (int mt = 0; mt < 4; ++mt) {
        const f32x4 bv = *(const f32x4*)(bias + 16 * mt + 4 * g);
#pragma unroll
        for (int r = 0; r < 4; ++r) {
            const int o = 16 * mt + 4 * g + r;
            op[(size_t)o * HW] = acc[mt][r] + bv[r];
        }
    }
}

// ---------------------------------------------------------------------------
// Fallback (round-7 NCHW path) if ws_size is too small.
// ---------------------------------------------------------------------------
__global__ void wt2_kernel(const float* __restrict__ w, short* __restrict__ wt2) {
    int i = blockIdx.x * 256 + threadIdx.x;
    if (i < 9 * COUT * CIN) {
        int c = i & 63, o = (i >> 6) & 63, t = i >> 12;
        wt2[i] = f2bf(w[(o * CIN + c) * 9 + t]);
    }
}

__global__ __launch_bounds__(256) void pdconv_mfma_kernel(
    const float* __restrict__ in, const short* __restrict__ wt2,
    const float* __restrict__ rate_map, const float* __restrict__ bias,
    float* __restrict__ out)
{
    const int tid = threadIdx.x, wave = tid >> 6, lane = tid & 63;
    const int px = lane & 15, g = lane >> 4;
    const int cpx = gridDim.x >> 3;
    const int bid = (blockIdx.x & 7) * cpx + (blockIdx.x >> 3);
    const int base = bid * 64 + wave * 16;
    const int b = base / HW, pix0 = base - b * HW;
    const int y = pix0 / WW, x0 = pix0 - y * WW, x = x0 + px;
    const float rate = rate_map[base + px];
    const float fy = (float)y, fx = (float)x;
    f32x4 acc[4];
#pragma unroll
    for (int mt = 0; mt < 4; ++mt) acc[mt] = (f32x4){0.f, 0.f, 0.f, 0.f};
    const float* img  = in + (size_t)b * CIN * HW;
    const float* imgg = img + (size_t)g * 8 * HW;
#pragma unroll 1
    for (int t = 0; t < 9; ++t) {
        const int ky = t / 3, kx = t - 3 * ky;
        const float sy = fy + (float)(ky - 1) * rate;
        const float sx = fx + (float)(kx - 1) * rate;
        const float y0f = floorf(sy), x0f = floorf(sx);
        const float wy = sy - y0f, wx = sx - x0f;
        const int y0 = (int)y0f, x0i = (int)x0f, y1 = y0 + 1, x1 = x0i + 1;
        const float omwy = 1.0f - wy, omwx = 1.0f - wx;
        const float vy0 = (y0 >= 0 && y0 < HH) ? 1.0f : 0.0f;
        const float vy1 = (y1 >= 0 && y1 < HH) ? 1.0f : 0.0f;
        const float vx0 = (x0i >= 0 && x0i < WW) ? 1.0f : 0.0f;
        const float vx1 = (x1 >= 0 && x1 < WW) ? 1.0f : 0.0f;
        const float c00 = omwy * omwx * vy0 * vx0, c01 = omwy * wx * vy0 * vx1;
        const float c10 = wy * omwx * vy1 * vx0,  c11 = wy * wx * vy1 * vx1;
        const int cy0 = min(max(y0, 0), HH - 1), cy1 = min(max(y1, 0), HH - 1);
        const int cx0 = min(max(x0i, 0), WW - 1), cx1 = min(max(x1, 0), WW - 1);
        const int i00 = cy0 * WW + cx0, i01 = cy0 * WW + cx1;
        const int i10 = cy1 * WW + cx0, i11 = cy1 * WW + cx1;
#pragma unroll
        for (int ks = 0; ks < 2; ++ks) {
            bf16x8 wf[4];
#pragma unroll
            for (int mt = 0; mt < 4; ++mt)
                wf[mt] = *(const bf16x8*)(wt2 +
                          ((t * COUT + 16 * mt + px) * CIN + 32 * ks + 8 * g));
            float a[8];
#pragma unroll
            for (int j = 0; j < 8; ++j) {
                const float* ch = imgg + (size_t)(32 * ks + j) * HW;
                a[j] = c00 * ch[i00] + c01 * ch[i01] + c10 * ch[i10] + c11 * ch[i11];
            }
            union { bf16x8 v; short s[8]; } pf;
#pragma unroll
            for (int j = 0; j < 8; ++j) pf.s[j] = f2bf(a[j]);
#pragma unroll
            for (int mt = 0; mt < 4; ++mt)
                acc[mt] = __builtin_amdgcn_mfma_f32_16x16x32_bf16(
                              wf[mt], pf.v, acc[mt], 0, 0, 0);
        }
    }
    float* op = out + (size_t)b * COUT * HW + pix0 + px;
#pragma unroll
    for (int mt = 0; mt < 4; ++mt)
#pragma unroll
        for (int r = 0; r < 4; ++r) {
            const int o = 16 * mt + 4 * g + r;
            op[(size_t)o * HW] = acc[mt][r] + bias[o];
        }
}

extern "C" void kernel_launch(void* const* d_in, const int* in_sizes, int n_in,
                              void* d_out, int out_size, void* d_ws, size_t ws_size,
                              hipStream_t stream) {
    (void)in_sizes; (void)n_in; (void)out_size;
    const float* in   = (const float*)d_in[0];
    const float* w    = (const float*)d_in[1];
    const float* rm   = (const float*)d_in[2];
    const float* bias = (const float*)d_in[3];
    float* out = (float*)d_out;

    const size_t WTF_BYTES = 36864 * sizeof(short);                 // 73,728
    const size_t TIN_BYTES = (size_t)NB * HW * CIN * sizeof(short); // 13,107,200

    if (ws_size >= WTF_BYTES + TIN_BYTES) {
        short* wtf = (short*)d_ws;
        short* tin = (short*)((char*)d_ws + WTF_BYTES);
        hipLaunchKernelGGL(wtf_kernel, dim3(144), dim3(256), 0, stream, w, wtf);
        hipLaunchKernelGGL(tin_kernel, dim3((NB * HW) / 256), dim3(256),
                           0, stream, in, tin);
        const int nblocks = NB * 80 * 5;   // 1600: 2x32 tiles
        hipLaunchKernelGGL(pdconv_halo_kernel, dim3(nblocks), dim3(256), 0,
                           stream, tin, wtf, rm, bias, out);
    } else {
        short* wt2 = (short*)d_ws;   // 73,728 B
        hipLaunchKernelGGL(wt2_kernel, dim3(144), dim3(256), 0, stream, w, wt2);
        hipLaunchKernelGGL(pdconv_mfma_kernel, dim3((NB * HW) / 64), dim3(256),
                           0, stream, in, wt2, rm, bias, out);
    }
}